// Round 5
// baseline (201.552 us; speedup 1.0000x reference)
//
#include <hip/hip_runtime.h>
#include <hip/hip_bf16.h>

#define GN 4096
#define GF 512
#define GH 8
#define GC 128
#define CAP 256          // max stored neighbors/row; deg ~ Bin(4096,0.01) = 41±6.4
#define BK 64
#define XS 72            // padded LDS stride in elems: 144 B = 16B-aligned

typedef __hip_bfloat16 bf16;
typedef unsigned short u16;
typedef unsigned int u32;
typedef __attribute__((ext_vector_type(8))) short bf16x8;   // 8 bf16 = 4 VGPRs
typedef __attribute__((ext_vector_type(4))) float f32x4;

static __device__ inline u16 f2u16(float x) {
    union { bf16 b; u16 u; } cv;
    cv.b = __float2bfloat16(x);
    return cv.u;
}

// ---------------------------------------------------------------------------
// Kernel 1 (MFMA): feats[h,n,:] = bf16(X[n,:]) @ bf16(W[h,:,:]), fp32 acc.
// BM=64 -> 512 blocks (>=2 blocks/CU co-resident so staging of one block
// overlaps MFMA of another — at 256 blocks there was no overlap partner).
// 256 thr = 4 waves; wave owns 16 rows x 128 cols = 8 accs of 16x16x32.
// ---------------------------------------------------------------------------
__global__ __launch_bounds__(256) void feats_kernel(
    const float* __restrict__ X, const float* __restrict__ W,
    const float* __restrict__ a_self, const float* __restrict__ a_neigh,
    bf16* __restrict__ featsb, float* __restrict__ s_self,
    float* __restrict__ s_neigh)
{
    __shared__ u16 sX[64 * XS];    //  9.2 KB
    __shared__ u16 sW[128 * XS];   // 18.4 KB

    int h   = blockIdx.x >> 6;
    int n0  = (blockIdx.x & 63) << 6;
    int tid = threadIdx.x;
    int lane = tid & 63, wv = tid >> 6;
    int lm = lane & 15, q = lane >> 4;

    const float* Xp = X + (size_t)n0 * GF;
    const float* Wh = W + (size_t)h * GF * GC;

    f32x4 acc[8];
#pragma unroll
    for (int nt = 0; nt < 8; ++nt) acc[nt] = (f32x4){0.f, 0.f, 0.f, 0.f};

    for (int k0 = 0; k0 < GF; k0 += BK) {
        __syncthreads();
        // stage X tile [64 m][64 k] fp32 -> bf16
#pragma unroll
        for (int it = 0; it < 4; ++it) {
            int idx = it * 256 + tid;
            int row = idx >> 4, q4 = idx & 15;
            float4 v = *(const float4*)&Xp[(size_t)row * GF + k0 + q4 * 4];
            u16* d = &sX[row * XS + q4 * 4];
            d[0] = f2u16(v.x); d[1] = f2u16(v.y);
            d[2] = f2u16(v.z); d[3] = f2u16(v.w);
        }
        // stage W^T tile [128 n][64 k]: coalesced read, scatter-transpose
#pragma unroll
        for (int it = 0; it < 8; ++it) {
            int idx = it * 256 + tid;
            int k = idx >> 5, n4 = idx & 31;
            float4 v = *(const float4*)&Wh[(size_t)(k0 + k) * GC + n4 * 4];
            sW[(n4 * 4 + 0) * XS + k] = f2u16(v.x);
            sW[(n4 * 4 + 1) * XS + k] = f2u16(v.y);
            sW[(n4 * 4 + 2) * XS + k] = f2u16(v.z);
            sW[(n4 * 4 + 3) * XS + k] = f2u16(v.w);
        }
        __syncthreads();

#pragma unroll
        for (int ks = 0; ks < BK; ks += 32) {
            bf16x8 af = *(const bf16x8*)&sX[(wv * 16 + lm) * XS + ks + q * 8];
            bf16x8 bfr[8];
#pragma unroll
            for (int nt = 0; nt < 8; ++nt)
                bfr[nt] = *(const bf16x8*)&sW[(nt * 16 + lm) * XS + ks + q * 8];
#pragma unroll
            for (int nt = 0; nt < 8; ++nt)
                acc[nt] = __builtin_amdgcn_mfma_f32_16x16x32_bf16(
                    af, bfr[nt], acc[nt], 0, 0, 0);
        }
    }

    // epilogue: bf16 feats store + fused s_self/s_neigh from fp32 accs
    float aS[8], aN[8];
#pragma unroll
    for (int nt = 0; nt < 8; ++nt) {
        aS[nt] = a_self[h * GC + nt * 16 + lm];
        aN[nt] = a_neigh[h * GC + nt * 16 + lm];
    }
    float vs[4] = {0.f, 0.f, 0.f, 0.f};
    float vn[4] = {0.f, 0.f, 0.f, 0.f};
    int rbase = n0 + wv * 16 + q * 4;          // D row = quad*4+reg (m89)
#pragma unroll
    for (int nt = 0; nt < 8; ++nt) {
        f32x4 v = acc[nt];
        int col = nt * 16 + lm;                // D col = lane&15
#pragma unroll
        for (int r = 0; r < 4; ++r) {
            featsb[((size_t)h * GN + rbase + r) * GC + col] = __float2bfloat16(v[r]);
            vs[r] += v[r] * aS[nt];
            vn[r] += v[r] * aN[nt];
        }
    }
#pragma unroll
    for (int r = 0; r < 4; ++r) {
        for (int off = 1; off < 16; off <<= 1) {
            vs[r] += __shfl_xor(vs[r], off);
            vn[r] += __shfl_xor(vn[r], off);
        }
        if (lm == 0) {
            s_self[h * GN + rbase + r]  = vs[r];
            s_neigh[h * GN + rbase + r] = vn[r];
        }
    }
}

// ---------------------------------------------------------------------------
// Kernel 2: A row -> compact u16 neighbor list via wave-ballot compaction
// (list order is irrelevant to softmax/gather). One shared atomic per wave
// per hit-containing component instead of per-lane divergent atomics.
// ---------------------------------------------------------------------------
__global__ __launch_bounds__(256) void csr_kernel(
    const float* __restrict__ A, int* __restrict__ deg,
    u16* __restrict__ lists)
{
    int i    = blockIdx.x;
    int tid  = threadIdx.x;
    int lane = tid & 63;
    __shared__ int cnt;
    if (tid == 0) cnt = 0;
    __syncthreads();

    u16* row = lists + (size_t)i * CAP;
    const float4* Arow = (const float4*)(A + (size_t)i * GN);
    unsigned long long ltmask = (lane == 63) ? ~0ull >> 1
                                             : (1ull << lane) - 1;
#pragma unroll
    for (int it = 0; it < 4; ++it) {
        int qd = it * 256 + tid;
        float4 a = Arow[qd];
        int j = qd * 4;
#pragma unroll
        for (int comp = 0; comp < 4; ++comp) {
            float av = comp == 0 ? a.x : comp == 1 ? a.y : comp == 2 ? a.z : a.w;
            bool flag = av > 0.5f;
            unsigned long long m = __ballot(flag);
            if (m) {
                int base = 0;
                if (lane == 0) base = atomicAdd(&cnt, __popcll(m));
                base = __shfl(base, 0);
                if (flag) {
                    int s = base + __popcll(m & ltmask);
                    if (s < CAP) row[s] = (u16)(j + comp);
                }
            }
        }
    }
    __syncthreads();
    if (tid == 0) deg[i] = cnt < CAP ? cnt : CAP;
}

// ---------------------------------------------------------------------------
// Kernel 3: one block per (h, i). (p, j) packed as float2 in LDS (single
// ds_read_b64 broadcast per neighbor). Gather: thread owns one DWORD
// (2 bf16 channels) of the feats row; the 2 waves split neighbors (k%2),
// partial sums combined through LDS at the end.
// ---------------------------------------------------------------------------
__global__ __launch_bounds__(128) void attn_kernel(
    const int* __restrict__ deg, const u16* __restrict__ lists,
    const float* __restrict__ bias, const bf16* __restrict__ featsb,
    const float* __restrict__ s_self, const float* __restrict__ s_neigh,
    float* __restrict__ out)
{
    int h   = blockIdx.x >> 12;        // GN = 4096
    int i   = blockIdx.x & (GN - 1);
    int tid = threadIdx.x;

    __shared__ float2 pj[CAP];         // .x = score/prob, .y = bitcast(j)
    __shared__ float  sacc[2][64][2];
    __shared__ float  redbuf[2];

    int M = deg[i];
    const u16* row = lists + (size_t)i * CAP;
    for (int k = tid; k < M; k += 128) pj[k].y = __int_as_float((int)row[k]);
    __syncthreads();

    float ssi = s_self[h * GN + i];
    const float* snh = s_neigh + h * GN;
    for (int k = tid; k < M; k += 128) {
        float e = ssi + snh[__float_as_int(pj[k].y)];
        pj[k].x = e > 0.f ? e : 0.2f * e;
    }
    __syncthreads();

    int lane = tid & 63, wv = tid >> 6;

    // block max
    float m = -1e30f;
    for (int k = tid; k < M; k += 128) m = fmaxf(m, pj[k].x);
    for (int off = 32; off > 0; off >>= 1) m = fmaxf(m, __shfl_down(m, off));
    if (lane == 0) redbuf[wv] = m;
    __syncthreads();
    m = fmaxf(redbuf[0], redbuf[1]);
    __syncthreads();

    // exp in place + block sum
    float s = 0.f;
    for (int k = tid; k < M; k += 128) {
        float e = __expf(pj[k].x - m);
        pj[k].x = e;
        s += e;
    }
    for (int off = 32; off > 0; off >>= 1) s += __shfl_down(s, off);
    __syncthreads();
    if (lane == 0) redbuf[wv] = s;
    __syncthreads();
    float inv = 1.f / (redbuf[0] + redbuf[1]);

    // gather: thread owns dword (channels 2c, 2c+1); wave wv takes k%2==wv
    int c2 = tid & 63;
    const u32* fh = (const u32*)(featsb + (size_t)h * GN * GC) + c2;
    float acc0 = 0.f, acc1 = 0.f;
#pragma unroll 2
    for (int k = wv; k < M; k += 2) {
        float2 v = pj[k];
        int j = __float_as_int(v.y);
        u32 u = fh[(size_t)j << 6];            // j*64 dwords
        float lo = __uint_as_float(u << 16);
        float hi = __uint_as_float(u & 0xffff0000u);
        acc0 += v.x * lo;
        acc1 += v.x * hi;
    }
    sacc[wv][c2][0] = acc0;
    sacc[wv][c2][1] = acc1;
    __syncthreads();

    if (tid < 64) {
        float r0 = (sacc[0][tid][0] + sacc[1][tid][0]) * inv + bias[h * GC + 2 * tid];
        float r1 = (sacc[0][tid][1] + sacc[1][tid][1]) * inv + bias[h * GC + 2 * tid + 1];
        float2* op = (float2*)&out[(size_t)i * (GH * GC) + h * GC + 2 * tid];
        *op = make_float2(fmaxf(r0, 0.f), fmaxf(r1, 0.f));
    }
}

// ---------------------------------------------------------------------------
extern "C" void kernel_launch(void* const* d_in, const int* in_sizes, int n_in,
                              void* d_out, int out_size, void* d_ws, size_t ws_size,
                              hipStream_t stream)
{
    const float* X       = (const float*)d_in[0];
    const float* A       = (const float*)d_in[1];
    const float* W       = (const float*)d_in[2];
    const float* a_self  = (const float*)d_in[3];
    const float* a_neigh = (const float*)d_in[4];
    const float* bias    = (const float*)d_in[5];
    float* out = (float*)d_out;

    // ws layout: featsb bf16 [H*N*C] | s_self f32 [H*N] | s_neigh f32 [H*N]
    //            | deg i32 [N] | lists u16 [N*CAP]
    bf16*  featsb  = (bf16*)d_ws;
    float* s_self  = (float*)(featsb + (size_t)GH * GN * GC);
    float* s_neigh = s_self + (size_t)GH * GN;
    int*   deg     = (int*)(s_neigh + (size_t)GH * GN);
    u16*   lists   = (u16*)(deg + GN);

    feats_kernel<<<GH * 64, 256, 0, stream>>>(X, W, a_self, a_neigh,
                                              featsb, s_self, s_neigh);
    csr_kernel<<<GN, 256, 0, stream>>>(A, deg, lists);
    attn_kernel<<<GH * GN, 128, 0, stream>>>(deg, lists, bias, featsb,
                                             s_self, s_neigh, out);
}

// Round 6
// 180.850 us; speedup vs baseline: 1.1145x; 1.1145x over previous
//
#include <hip/hip_runtime.h>
#include <hip/hip_bf16.h>

#define GN 4096
#define GF 512
#define GH 8
#define GC 128
#define CAP 256          // max stored neighbors/row; deg ~ Bin(4096,0.01) = 41±6.4
#define BK 64
#define XS 72            // padded LDS stride in elems: 144 B = 16B-aligned

typedef __hip_bfloat16 bf16;
typedef unsigned short u16;
typedef unsigned int u32;
typedef __attribute__((ext_vector_type(8))) short bf16x8;   // 8 bf16 = 4 VGPRs
typedef __attribute__((ext_vector_type(4))) float f32x4;

static __device__ inline u16 f2u16(float x) {
    union { bf16 b; u16 u; } cv;
    cv.b = __float2bfloat16(x);
    return cv.u;
}

// ---------------------------------------------------------------------------
// Kernel 1 (MFMA): feats[h,n,:] = bf16(X[n,:]) @ bf16(W[h,:,:]), fp32 acc.
// BM=64 -> 512 blocks (>=2 blocks/CU). Software-pipelined staging: global
// loads for tile t+1 are issued into registers BEFORE the MFMA loop on tile
// t, so VMEM latency overlaps MFMA + barrier; cvt+LDS-write happens after
// the post-MFMA barrier.
// ---------------------------------------------------------------------------
__global__ __launch_bounds__(256) void feats_kernel(
    const float* __restrict__ X, const float* __restrict__ W,
    const float* __restrict__ a_self, const float* __restrict__ a_neigh,
    bf16* __restrict__ featsb, float* __restrict__ s_self,
    float* __restrict__ s_neigh)
{
    __shared__ u16 sX[64 * XS];    //  9.2 KB
    __shared__ u16 sW[128 * XS];   // 18.4 KB

    int h   = blockIdx.x >> 6;
    int n0  = (blockIdx.x & 63) << 6;
    int tid = threadIdx.x;
    int lane = tid & 63, wv = tid >> 6;
    int lm = lane & 15, q = lane >> 4;

    const float* Xp = X + (size_t)n0 * GF;
    const float* Wh = W + (size_t)h * GF * GC;

    // per-thread staging slots
    int xrow = tid >> 4, xq4 = tid & 15;           // X: 4 iters of 256
    int wk = tid >> 5, wn4 = tid & 31;             // W: 8 iters of 256

    float4 xr[4], wr[8];

#define ISSUE_TILE(K0)                                                        \
    {                                                                         \
        _Pragma("unroll")                                                     \
        for (int it = 0; it < 4; ++it)                                        \
            xr[it] = *(const float4*)&Xp[(size_t)(it * 16 + xrow) * GF +      \
                                         (K0) + xq4 * 4];                     \
        _Pragma("unroll")                                                     \
        for (int it = 0; it < 8; ++it)                                        \
            wr[it] = *(const float4*)&Wh[(size_t)((K0) + it * 8 + wk) * GC +  \
                                         wn4 * 4];                            \
    }

#define STORE_TILE()                                                          \
    {                                                                         \
        _Pragma("unroll")                                                     \
        for (int it = 0; it < 4; ++it) {                                      \
            u16* d = &sX[(it * 16 + xrow) * XS + xq4 * 4];                    \
            d[0] = f2u16(xr[it].x); d[1] = f2u16(xr[it].y);                   \
            d[2] = f2u16(xr[it].z); d[3] = f2u16(xr[it].w);                   \
        }                                                                     \
        _Pragma("unroll")                                                     \
        for (int it = 0; it < 8; ++it) {                                      \
            int k = it * 8 + wk;                                              \
            sW[(wn4 * 4 + 0) * XS + k] = f2u16(wr[it].x);                     \
            sW[(wn4 * 4 + 1) * XS + k] = f2u16(wr[it].y);                     \
            sW[(wn4 * 4 + 2) * XS + k] = f2u16(wr[it].z);                     \
            sW[(wn4 * 4 + 3) * XS + k] = f2u16(wr[it].w);                     \
        }                                                                     \
    }

    f32x4 acc[8];
#pragma unroll
    for (int nt = 0; nt < 8; ++nt) acc[nt] = (f32x4){0.f, 0.f, 0.f, 0.f};

    ISSUE_TILE(0)
    STORE_TILE()

    for (int k0 = 0; k0 < GF; k0 += BK) {
        __syncthreads();                       // tile k0 visible to all
        if (k0 + BK < GF) ISSUE_TILE(k0 + BK)  // next tile loads in flight

#pragma unroll
        for (int ks = 0; ks < BK; ks += 32) {
            bf16x8 af = *(const bf16x8*)&sX[(wv * 16 + lm) * XS + ks + q * 8];
            bf16x8 bfr[8];
#pragma unroll
            for (int nt = 0; nt < 8; ++nt)
                bfr[nt] = *(const bf16x8*)&sW[(nt * 16 + lm) * XS + ks + q * 8];
#pragma unroll
            for (int nt = 0; nt < 8; ++nt)
                acc[nt] = __builtin_amdgcn_mfma_f32_16x16x32_bf16(
                    af, bfr[nt], acc[nt], 0, 0, 0);
        }
        __syncthreads();                       // all readers done with k0
        if (k0 + BK < GF) STORE_TILE()
    }

    // epilogue: bf16 feats store + fused s_self/s_neigh from fp32 accs
    float aS[8], aN[8];
#pragma unroll
    for (int nt = 0; nt < 8; ++nt) {
        aS[nt] = a_self[h * GC + nt * 16 + lm];
        aN[nt] = a_neigh[h * GC + nt * 16 + lm];
    }
    float vs[4] = {0.f, 0.f, 0.f, 0.f};
    float vn[4] = {0.f, 0.f, 0.f, 0.f};
    int rbase = n0 + wv * 16 + q * 4;          // D row = quad*4+reg (m89)
#pragma unroll
    for (int nt = 0; nt < 8; ++nt) {
        f32x4 v = acc[nt];
        int col = nt * 16 + lm;                // D col = lane&15
#pragma unroll
        for (int r = 0; r < 4; ++r) {
            featsb[((size_t)h * GN + rbase + r) * GC + col] = __float2bfloat16(v[r]);
            vs[r] += v[r] * aS[nt];
            vn[r] += v[r] * aN[nt];
        }
    }
#pragma unroll
    for (int r = 0; r < 4; ++r) {
        for (int off = 1; off < 16; off <<= 1) {
            vs[r] += __shfl_xor(vs[r], off);
            vn[r] += __shfl_xor(vn[r], off);
        }
        if (lm == 0) {
            s_self[h * GN + rbase + r]  = vs[r];
            s_neigh[h * GN + rbase + r] = vn[r];
        }
    }
#undef ISSUE_TILE
#undef STORE_TILE
}

// ---------------------------------------------------------------------------
// Kernel 2: A row -> compact u16 neighbor list via wave-ballot compaction.
// ---------------------------------------------------------------------------
__global__ __launch_bounds__(256) void csr_kernel(
    const float* __restrict__ A, int* __restrict__ deg,
    u16* __restrict__ lists)
{
    int i    = blockIdx.x;
    int tid  = threadIdx.x;
    int lane = tid & 63;
    __shared__ int cnt;
    if (tid == 0) cnt = 0;
    __syncthreads();

    u16* row = lists + (size_t)i * CAP;
    const float4* Arow = (const float4*)(A + (size_t)i * GN);
    unsigned long long ltmask = (lane == 63) ? ~0ull >> 1
                                             : (1ull << lane) - 1;
#pragma unroll
    for (int it = 0; it < 4; ++it) {
        int qd = it * 256 + tid;
        float4 a = Arow[qd];
        int j = qd * 4;
#pragma unroll
        for (int comp = 0; comp < 4; ++comp) {
            float av = comp == 0 ? a.x : comp == 1 ? a.y : comp == 2 ? a.z : a.w;
            bool flag = av > 0.5f;
            unsigned long long m = __ballot(flag);
            if (m) {
                int base = 0;
                if (lane == 0) base = atomicAdd(&cnt, __popcll(m));
                base = __shfl(base, 0);
                if (flag) {
                    int s = base + __popcll(m & ltmask);
                    if (s < CAP) row[s] = (u16)(j + comp);
                }
            }
        }
    }
    __syncthreads();
    if (tid == 0) deg[i] = cnt < CAP ? cnt : CAP;
}

// ---------------------------------------------------------------------------
// Kernel 3: ONE WAVE per (h, i) — zero barriers, 4 independent waves per
// block. Per-wave 2 KB LDS (p, j) list (same-wave LDS round-trip needs only
// lgkmcnt, no __syncthreads). Wave-shuffle softmax; gather with lane = dword
// (2 bf16 channels), 64 lanes cover the 128-ch row.
// ---------------------------------------------------------------------------
__global__ __launch_bounds__(256) void attn_kernel(
    const int* __restrict__ deg, const u16* __restrict__ lists,
    const float* __restrict__ bias, const bf16* __restrict__ featsb,
    const float* __restrict__ s_self, const float* __restrict__ s_neigh,
    float* __restrict__ out)
{
    int tid  = threadIdx.x;
    int wv   = tid >> 6, lane = tid & 63;
    int g    = blockIdx.x * 4 + wv;        // wave-global id, h-major
    int h    = g >> 12;                    // GN = 4096
    int i    = g & (GN - 1);

    __shared__ float2 pjbuf[4][CAP];       // 8 KB
    float2* pj = pjbuf[wv];

    int M = deg[i];
    const u16* row = lists + (size_t)i * CAP;
    float ssi = s_self[h * GN + i];
    const float* snh = s_neigh + h * GN;

    // pass 1: leaky scores -> LDS, lane-local max
    float lmax = -1e30f;
    for (int k = lane; k < M; k += 64) {
        int j = row[k];
        float e = ssi + snh[j];
        e = e > 0.f ? e : 0.2f * e;
        pj[k] = make_float2(e, __int_as_float(j));
        lmax = fmaxf(lmax, e);
    }
#pragma unroll
    for (int off = 32; off > 0; off >>= 1)
        lmax = fmaxf(lmax, __shfl_xor(lmax, off));

    // pass 2: exp in place + sum
    float lsum = 0.f;
    for (int k = lane; k < M; k += 64) {
        float e = __expf(pj[k].x - lmax);
        pj[k].x = e;
        lsum += e;
    }
#pragma unroll
    for (int off = 32; off > 0; off >>= 1) lsum += __shfl_xor(lsum, off);
    float inv = 1.f / lsum;

    // gather: lane owns dword (channels 2*lane, 2*lane+1)
    const u32* fh = (const u32*)(featsb + (size_t)h * GN * GC) + lane;
    float acc0 = 0.f, acc1 = 0.f;
#pragma unroll 4
    for (int k = 0; k < M; ++k) {
        float2 v = pj[k];                  // wave-uniform addr -> broadcast
        int j = __float_as_int(v.y);
        u32 u = fh[(size_t)j << 6];        // j*64 dwords
        acc0 += v.x * __uint_as_float(u << 16);
        acc1 += v.x * __uint_as_float(u & 0xffff0000u);
    }

    const float2 bv = *(const float2*)&bias[h * GC + 2 * lane];
    float r0 = acc0 * inv + bv.x;
    float r1 = acc1 * inv + bv.y;
    float2* op = (float2*)&out[(size_t)i * (GH * GC) + h * GC + 2 * lane];
    *op = make_float2(fmaxf(r0, 0.f), fmaxf(r1, 0.f));
}

// ---------------------------------------------------------------------------
extern "C" void kernel_launch(void* const* d_in, const int* in_sizes, int n_in,
                              void* d_out, int out_size, void* d_ws, size_t ws_size,
                              hipStream_t stream)
{
    const float* X       = (const float*)d_in[0];
    const float* A       = (const float*)d_in[1];
    const float* W       = (const float*)d_in[2];
    const float* a_self  = (const float*)d_in[3];
    const float* a_neigh = (const float*)d_in[4];
    const float* bias    = (const float*)d_in[5];
    float* out = (float*)d_out;

    // ws layout: featsb bf16 [H*N*C] | s_self f32 [H*N] | s_neigh f32 [H*N]
    //            | deg i32 [N] | lists u16 [N*CAP]
    bf16*  featsb  = (bf16*)d_ws;
    float* s_self  = (float*)(featsb + (size_t)GH * GN * GC);
    float* s_neigh = s_self + (size_t)GH * GN;
    int*   deg     = (int*)(s_neigh + (size_t)GH * GN);
    u16*   lists   = (u16*)(deg + GN);

    feats_kernel<<<GH * 64, 256, 0, stream>>>(X, W, a_self, a_neigh,
                                              featsb, s_self, s_neigh);
    csr_kernel<<<GN, 256, 0, stream>>>(A, deg, lists);
    attn_kernel<<<GH * GN / 4, 256, 0, stream>>>(deg, lists, bias, featsb,
                                                 s_self, s_neigh, out);
}